// Round 1
// baseline (304.463 us; speedup 1.0000x reference)
//
#include <hip/hip_runtime.h>
#include <math.h>

typedef short s16x8 __attribute__((ext_vector_type(8)));
typedef float f32x4 __attribute__((ext_vector_type(4)));

#define MFMA(a, b, c)   __builtin_amdgcn_mfma_f32_16x16x32_bf16(a, b, c, 0, 0, 0)

__device__ __forceinline__ float b2f(ushort u) {
    union { unsigned int i; float f; } v; v.i = ((unsigned int)u) << 16; return v.f;
}
__device__ __forceinline__ ushort f2b(float f) {
    union { float f; unsigned int i; } v; v.f = f;
    unsigned int r = v.i + 0x7fffu + ((v.i >> 16) & 1u);
    return (ushort)(r >> 16);
}
__device__ __forceinline__ float gelu_tanh(float v) {
    float u = 0.7978845608f * (v + 0.044715f * v * v * v);
    float e = __expf(-2.f * fabsf(u));
    float t = (1.f - e) / (1.f + e);            // tanh(|u|)
    t = (u < 0.f) ? -t : t;
    return 0.5f * v * (1.f + t);
}

// ---------------------------------------------------------------------------
// K0: all prep. blocks [0,192): qkv_w->wq; [192,256): proj_w->wp;
// [256,768): fc1/fc2->wf; [768,832): bias+mask table bm[cls][head][128][128].
// ---------------------------------------------------------------------------
__global__ __launch_bounds__(256) void k0_prep(
    const float* __restrict__ qkv_w, const float* __restrict__ proj_w,
    const float* __restrict__ fc1_w, const float* __restrict__ fc2_w,
    const float* __restrict__ rpb, ushort* __restrict__ wq,
    ushort* __restrict__ wp, ushort* __restrict__ wf, ushort* __restrict__ bm)
{
    int bid = blockIdx.x, tid = threadIdx.x;
    if (bid < 192) { int idx = bid * 256 + tid; wq[idx] = f2b(qkv_w[idx]); return; }
    if (bid < 256) { int idx = (bid - 192) * 256 + tid; wp[idx] = f2b(proj_w[idx]); return; }
    if (bid < 768) {
        int idx = (bid - 256) * 256 + tid;
        wf[idx] = f2b(idx < 65536 ? fc1_w[idx] : fc2_w[idx - 65536]);
        return;
    }
    int bi = bid - 768;                             // [0,64) = cls*8+head
    int cls = bi >> 3, head = bi & 7;
    int ed = (cls >> 2) & 1, eh = (cls >> 1) & 1, ew = cls & 1;
    int j = tid & 127;
    int tdj = j >> 6, thj = (j >> 3) & 7, twj = j & 7;
    int regj = (ed ? (tdj + 1) : 0) * 9
             + (eh ? ((thj < 4) ? 1 : 2) : 0) * 3
             + (ew ? ((twj < 4) ? 1 : 2) : 0);
    ushort* bmp = bm + (long)bi * 16384;
    for (int ii = 0; ii < 64; ++ii) {
        int i = (tid >> 7) * 64 + ii;
        int tdi = i >> 6, thi = (i >> 3) & 7, twi = i & 7;
        int regi = (ed ? (tdi + 1) : 0) * 9
                 + (eh ? ((thi < 4) ? 1 : 2) : 0) * 3
                 + (ew ? ((twi < 4) ? 1 : 2) : 0);
        int rpi = (tdi - tdj + 1) * 225 + (thi - thj + 7) * 15 + (twi - twj + 7);
        float v = rpb[rpi * 8 + head] + ((regi != regj) ? -100.f : 0.f);
        bmp[i * 128 + j] = f2b(v);
    }
}

// ---------------------------------------------------------------------------
// K2: fused LN1 + cyclic-shift + window gather + QKV GEMM.
// Output WINDOW-major: qkv[wi][mat][head][token][16] (strides 49152/16384/2048/16).
// ---------------------------------------------------------------------------
__global__ __launch_bounds__(256) void k2_qkv(
    const float* __restrict__ x, const float* __restrict__ g,
    const float* __restrict__ be, const ushort* __restrict__ wq,
    const float* __restrict__ qkv_b, ushort* __restrict__ qkv)
{
    __shared__ __align__(16) ushort As[128][136];
    int tid = threadIdx.x;
    int m0 = blockIdx.x * 128;
    {   // LN + shift + gather -> As (2 threads per row)
        int row = tid >> 1, half = tid & 1;
        int tk = m0 + row;
        int wi = tk >> 7, t = tk & 127;
        int b = wi >> 8, wd = (wi >> 6) & 3, wh = (wi >> 3) & 7, ww = wi & 7;
        int td = t >> 6, th = (t >> 3) & 7, tw = t & 7;
        int d = (wd * 2 + td + 1) & 7;
        int h = (wh * 8 + th + 4) & 63;
        int w = (ww * 8 + tw + 4) & 63;
        long src = (((long)((b * 8 + d) * 64 + h)) * 64 + w) * 128 + half * 64;
        float vals[64];
        float s = 0.f, q = 0.f;
        #pragma unroll
        for (int i = 0; i < 16; ++i) {
            float4 u = *(const float4*)&x[src + i * 4];
            vals[i * 4 + 0] = u.x; vals[i * 4 + 1] = u.y;
            vals[i * 4 + 2] = u.z; vals[i * 4 + 3] = u.w;
            s += u.x + u.y + u.z + u.w;
            q += u.x * u.x + u.y * u.y + u.z * u.z + u.w * u.w;
        }
        s += __shfl_xor(s, 1);
        q += __shfl_xor(q, 1);
        float mean = s * (1.f / 128.f);
        float rstd = rsqrtf(q * (1.f / 128.f) - mean * mean + 1e-5f);
        #pragma unroll
        for (int i = 0; i < 8; ++i) {
            ushort pk[8];
            #pragma unroll
            for (int jj = 0; jj < 8; ++jj) {
                int c = half * 64 + i * 8 + jj;
                pk[jj] = f2b((vals[i * 8 + jj] - mean) * rstd * g[c] + be[c]);
            }
            *(uint4*)&As[row][half * 64 + i * 8] = *(uint4*)pk;
        }
    }
    __syncthreads();
    int wv = tid >> 6, lane = tid & 63, li = lane & 15, quad = lane >> 4;
    int wm = wv >> 1, wn = wv & 1;
    long wibase = (long)(m0 >> 7) * 49152;
    for (int nb = 0; nb < 3; ++nb) {
        f32x4 acc[4][4] = {};
        for (int s = 0; s < 4; ++s) {
            s16x8 a[4], bw[4];
            #pragma unroll
            for (int mi = 0; mi < 4; ++mi)
                a[mi] = *(const s16x8*)&As[wm * 64 + mi * 16 + li][s * 32 + quad * 8];
            #pragma unroll
            for (int ni = 0; ni < 4; ++ni)
                bw[ni] = *(const s16x8*)&wq[(long)(nb * 128 + wn * 64 + ni * 16 + li) * 128
                                            + s * 32 + quad * 8];
            #pragma unroll
            for (int mi = 0; mi < 4; ++mi)
                #pragma unroll
                for (int ni = 0; ni < 4; ++ni)
                    acc[mi][ni] = MFMA(a[mi], bw[ni], acc[mi][ni]);
        }
        #pragma unroll
        for (int mi = 0; mi < 4; ++mi)
            #pragma unroll
            for (int ni = 0; ni < 4; ++ni) {
                int gcol = nb * 128 + wn * 64 + ni * 16 + li;
                int mat = gcol >> 7, hd = (gcol >> 4) & 7;
                float bias = qkv_b[gcol];
                float scale = (mat == 0) ? 0.25f : 1.f;   // SCALE = 16^-0.5
                long base2 = wibase + mat * 16384 + hd * 2048 + li;
                #pragma unroll
                for (int r = 0; r < 4; ++r) {
                    int trow = wm * 64 + mi * 16 + quad * 4 + r;
                    qkv[base2 + trow * 16] = f2b((acc[mi][ni][r] + bias) * scale);
                }
            }
    }
}

// ---------------------------------------------------------------------------
// K3: one block per WINDOW, 8 heads sequential. QK^T (16x16x32, d zero-padded),
// bias+mask table, softmax, PV. O held in registers across heads, then written
// in-place over the (dead) q-region of this window: ao[wi][token][128ch].
// ---------------------------------------------------------------------------
__global__ __launch_bounds__(256) void k3_attn(
    ushort* __restrict__ qkv, const ushort* __restrict__ bm)
{
    __shared__ __align__(16) ushort qs[128][40];
    __shared__ __align__(16) ushort ks[128][40];
    __shared__ __align__(16) ushort vt[16][136];
    __shared__ __align__(16) ushort ps[128][136];
    int wi = blockIdx.x;
    int wd = (wi >> 6) & 3, wh = (wi >> 3) & 7, ww = wi & 7;
    int cls = ((wd == 3) << 2) | ((wh == 7) << 1) | (ww == 7);
    int tid = threadIdx.x;
    int wv = tid >> 6, lane = tid & 63, li = lane & 15, quad = lane >> 4;
    long wbase = (long)wi * 49152;
    uint2 opk[8][2];
    for (int h = 0; h < 8; ++h) {
        __syncthreads();   // previous head's PV readers done before restage
        {   int token = tid >> 1, dd0 = (tid & 1) * 8;
            long tb = wbase + h * 2048 + token * 16 + dd0;
            uint4 qv = *(const uint4*)&qkv[tb];
            uint4 kv = *(const uint4*)&qkv[tb + 16384];
            uint4 vv = *(const uint4*)&qkv[tb + 32768];
            uint4 z = {0, 0, 0, 0};
            *(uint4*)&qs[token][dd0] = qv;
            *(uint4*)&ks[token][dd0] = kv;
            *(uint4*)&qs[token][16 + dd0] = z;
            *(uint4*)&ks[token][16 + dd0] = z;
            const ushort* pv = (const ushort*)&vv;
            #pragma unroll
            for (int j = 0; j < 8; ++j) vt[dd0 + j][token] = pv[j];
        }
        __syncthreads();
        f32x4 sacc[2][8] = {};
        s16x8 a[2];
        #pragma unroll
        for (int mi = 0; mi < 2; ++mi)
            a[mi] = *(const s16x8*)&qs[wv * 32 + mi * 16 + li][quad * 8];
        #pragma unroll
        for (int ni = 0; ni < 8; ++ni) {
            s16x8 bf = *(const s16x8*)&ks[ni * 16 + li][quad * 8];
            #pragma unroll
            for (int mi = 0; mi < 2; ++mi) sacc[mi][ni] = MFMA(a[mi], bf, sacc[mi][ni]);
        }
        long bmbase = (long)(cls * 8 + h) * 16384;
        #pragma unroll
        for (int mi = 0; mi < 2; ++mi) {
            #pragma unroll
            for (int r = 0; r < 4; ++r) {
                int i = wv * 32 + mi * 16 + quad * 4 + r;
                float sv[8];
                float rowmax = -1e30f;
                #pragma unroll
                for (int ni = 0; ni < 8; ++ni) {
                    float v = sacc[mi][ni][r] + b2f(bm[bmbase + i * 128 + ni * 16 + li]);
                    sv[ni] = v;
                    rowmax = fmaxf(rowmax, v);
                }
                #pragma unroll
                for (int m = 1; m < 16; m <<= 1) rowmax = fmaxf(rowmax, __shfl_xor(rowmax, m));
                float sum = 0.f;
                #pragma unroll
                for (int ni = 0; ni < 8; ++ni) { sv[ni] = __expf(sv[ni] - rowmax); sum += sv[ni]; }
                #pragma unroll
                for (int m = 1; m < 16; m <<= 1) sum += __shfl_xor(sum, m);
                float inv = 1.f / sum;
                #pragma unroll
                for (int ni = 0; ni < 8; ++ni) ps[i][ni * 16 + li] = f2b(sv[ni] * inv);
            }
        }
        __syncthreads();
        f32x4 pacc[2] = {};
        #pragma unroll
        for (int kk = 0; kk < 4; ++kk) {
            s16x8 bv = *(const s16x8*)&vt[li][kk * 32 + quad * 8];
            #pragma unroll
            for (int mi = 0; mi < 2; ++mi) {
                s16x8 ap = *(const s16x8*)&ps[wv * 32 + mi * 16 + li][kk * 32 + quad * 8];
                pacc[mi] = MFMA(ap, bv, pacc[mi]);
            }
        }
        #pragma unroll
        for (int mi = 0; mi < 2; ++mi) {
            opk[h][mi].x = (unsigned int)f2b(pacc[mi][0]) | ((unsigned int)f2b(pacc[mi][1]) << 16);
            opk[h][mi].y = (unsigned int)f2b(pacc[mi][2]) | ((unsigned int)f2b(pacc[mi][3]) << 16);
        }
    }
    // all q/k/v of this window consumed -> safe to overwrite q-region with O
    #pragma unroll
    for (int h = 0; h < 8; ++h)
        #pragma unroll
        for (int mi = 0; mi < 2; ++mi) {
            unsigned int w0 = opk[h][mi].x, w1 = opk[h][mi].y;
            #pragma unroll
            for (int r = 0; r < 4; ++r) {
                unsigned int word = (r < 2) ? w0 : w1;
                ushort v = (ushort)((word >> ((r & 1) * 16)) & 0xffff);
                int i = wv * 32 + mi * 16 + quad * 4 + r;
                qkv[wbase + (long)i * 128 + h * 16 + li] = v;
            }
        }
}

// ---------------------------------------------------------------------------
// K45: fused proj GEMM + bias + residual + LN2 + FC1 + gelu + FC2 + residual
// + window-reverse/unshift scattered f32 store. 64-token tile, 1024 blocks.
// R1: x1 kept in 16 packed bf16x2 VGPRs (was 16.9KB x1t LDS); LN2 stats via
// 16-lane shfl butterfly + redS[2][64] cross-wave combine. LDS 52.7->34.8KB
// => 4 blocks/CU (was 3). Final residual added in f32.
// ---------------------------------------------------------------------------
__global__ __launch_bounds__(256, 4) void k45(
    const ushort* __restrict__ ao, const ushort* __restrict__ wp,
    const float* __restrict__ proj_b, const float* __restrict__ x,
    const float* __restrict__ g2, const float* __restrict__ be2,
    const ushort* __restrict__ wf1, const float* __restrict__ fc1_b,
    const ushort* __restrict__ wf2, const float* __restrict__ fc2_b,
    float* __restrict__ out)
{
    __shared__ __align__(16) ushort As[64][132];    // ao tile, later xs (LN2 out)
    __shared__ __align__(16) ushort hs[64][132];    // gelu(h) chunk
    __shared__ float redS[2][64];
    __shared__ float redQ[2][64];
    int tid = threadIdx.x;
    int b = blockIdx.x;
    int wi = b >> 1, half64 = b & 1;
    int wd = (wi >> 6) & 3, wh = (wi >> 3) & 7, ww = wi & 7;
    int bb = wi >> 8;
    long aobase = (long)wi * 49152 + half64 * 8192;
    #pragma unroll
    for (int i = 0; i < 4; ++i) {
        int slot = tid + i * 256;
        int row = slot >> 4, c8 = (slot & 15) * 8;
        *(uint4*)&As[row][c8] = *(const uint4*)&ao[aobase + row * 128 + c8];
    }
    __syncthreads();
    int wv = tid >> 6, lane = tid & 63, li = lane & 15, quad = lane >> 4;
    int wm = wv >> 1, wn = wv & 1;
    f32x4 acc[2][4] = {};
    for (int s = 0; s < 4; ++s) {
        s16x8 a[2], bw[4];
        #pragma unroll
        for (int mi = 0; mi < 2; ++mi)
            a[mi] = *(const s16x8*)&As[wm * 32 + mi * 16 + li][s * 32 + quad * 8];
        #pragma unroll
        for (int ni = 0; ni < 4; ++ni)
            bw[ni] = *(const s16x8*)&wp[(long)(wn * 64 + ni * 16 + li) * 128 + s * 32 + quad * 8];
        #pragma unroll
        for (int mi = 0; mi < 2; ++mi)
            #pragma unroll
            for (int ni = 0; ni < 4; ++ni)
                acc[mi][ni] = MFMA(a[mi], bw[ni], acc[mi][ni]);
    }
    // epilogue: x1 = acc + proj_b + x (f32, in-place in acc); LN2 row partials
    int cols[4];
    #pragma unroll
    for (int ni = 0; ni < 4; ++ni) cols[ni] = wn * 64 + ni * 16 + li;
    {
        float pbv[4];
        #pragma unroll
        for (int ni = 0; ni < 4; ++ni) pbv[ni] = proj_b[cols[ni]];
        #pragma unroll
        for (int mi = 0; mi < 2; ++mi) {
            #pragma unroll
            for (int r = 0; r < 4; ++r) {
                int lrow = wm * 32 + mi * 16 + quad * 4 + r;
                int t = half64 * 64 + lrow;
                int td = t >> 6, th = (t >> 3) & 7, tw = t & 7;
                int d = (wd * 2 + td + 1) & 7, h = (wh * 8 + th + 4) & 63, w = (ww * 8 + tw + 4) & 63;
                long di = (((long)((bb * 8 + d) * 64 + h)) * 64 + w) * 128;
                float s_ = 0.f, q_ = 0.f;
                #pragma unroll
                for (int ni = 0; ni < 4; ++ni) {
                    float v = acc[mi][ni][r] + pbv[ni] + x[di + cols[ni]];
                    acc[mi][ni][r] = v;
                    s_ += v; q_ += v * v;
                }
                #pragma unroll
                for (int m = 1; m < 16; m <<= 1) {
                    s_ += __shfl_xor(s_, m);
                    q_ += __shfl_xor(q_, m);
                }
                if (li == 0) { redS[wn][lrow] = s_; redQ[wn][lrow] = q_; }
            }
        }
    }
    __syncthreads();
    // LN2 normalize -> As (xs); pack x1 -> bf16x2 regs
    {
        float g2v[4], be2v[4];
        #pragma unroll
        for (int ni = 0; ni < 4; ++ni) { g2v[ni] = g2[cols[ni]]; be2v[ni] = be2[cols[ni]]; }
        #pragma unroll
        for (int mi = 0; mi < 2; ++mi) {
            #pragma unroll
            for (int r = 0; r < 4; ++r) {
                int lrow = wm * 32 + mi * 16 + quad * 4 + r;
                float tS = redS[0][lrow] + redS[1][lrow];
                float tQ = redQ[0][lrow] + redQ[1][lrow];
                float mean = tS * (1.f / 128.f);
                float rstd = rsqrtf(tQ * (1.f / 128.f) - mean * mean + 1e-5f);
                #pragma unroll
                for (int ni = 0; ni < 4; ++ni)
                    As[lrow][cols[ni]] = f2b((acc[mi][ni][r] - mean) * rstd * g2v[ni] + be2v[ni]);
            }
        }
    }
    uint x1p[2][4][2];
    #pragma unroll
    for (int mi = 0; mi < 2; ++mi)
        #pragma unroll
        for (int ni = 0; ni < 4; ++ni)
            #pragma unroll
            for (int rr = 0; rr < 2; ++rr)
                x1p[mi][ni][rr] = (unsigned int)f2b(acc[mi][ni][2 * rr])
                                | ((unsigned int)f2b(acc[mi][ni][2 * rr + 1]) << 16);
    __syncthreads();
    f32x4 yacc[2][4] = {};
    for (int hc = 0; hc < 4; ++hc) {
        f32x4 hacc[2][4] = {};
        #pragma unroll
        for (int kk = 0; kk < 4; ++kk) {
            s16x8 a[2], bw[4];
            #pragma unroll
            for (int mi = 0; mi < 2; ++mi)
                a[mi] = *(const s16x8*)&As[wm * 32 + mi * 16 + li][kk * 32 + quad * 8];
            #pragma unroll
            for (int ni = 0; ni < 4; ++ni)
                bw[ni] = *(const s16x8*)&wf1[(long)(hc * 128 + wn * 64 + ni * 16 + li) * 128
                                             + kk * 32 + quad * 8];
            #pragma unroll
            for (int mi = 0; mi < 2; ++mi)
                #pragma unroll
                for (int ni = 0; ni < 4; ++ni)
                    hacc[mi][ni] = MFMA(a[mi], bw[ni], hacc[mi][ni]);
        }
        #pragma unroll
        for (int mi = 0; mi < 2; ++mi)
            #pragma unroll
            for (int ni = 0; ni < 4; ++ni) {
                int col = wn * 64 + ni * 16 + li;
                float bbv = fc1_b[hc * 128 + col];
                #pragma unroll
                for (int r = 0; r < 4; ++r) {
                    int row = wm * 32 + mi * 16 + quad * 4 + r;
                    hs[row][col] = f2b(gelu_tanh(hacc[mi][ni][r] + bbv));
                }
            }
        __syncthreads();
        #pragma unroll
        for (int kk = 0; kk < 4; ++kk) {
            s16x8 a[2], bw[4];
            #pragma unroll
            for (int mi = 0; mi < 2; ++mi)
                a[mi] = *(const s16x8*)&hs[wm * 32 + mi * 16 + li][kk * 32 + quad * 8];
            #pragma unroll
            for (int ni = 0; ni < 4; ++ni)
                bw[ni] = *(const s16x8*)&wf2[(long)(wn * 64 + ni * 16 + li) * 512
                                             + hc * 128 + kk * 32 + quad * 8];
            #pragma unroll
            for (int mi = 0; mi < 2; ++mi)
                #pragma unroll
                for (int ni = 0; ni < 4; ++ni)
                    yacc[mi][ni] = MFMA(a[mi], bw[ni], yacc[mi][ni]);
        }
        __syncthreads();
    }
    {
        float f2v[4];
        #pragma unroll
        for (int ni = 0; ni < 4; ++ni) f2v[ni] = fc2_b[cols[ni]];
        #pragma unroll
        for (int mi = 0; mi < 2; ++mi) {
            #pragma unroll
            for (int r = 0; r < 4; ++r) {
                int lrow = wm * 32 + mi * 16 + quad * 4 + r;
                int t = half64 * 64 + lrow;
                int td = t >> 6, th = (t >> 3) & 7, tw = t & 7;
                int d = (wd * 2 + td + 1) & 7, h = (wh * 8 + th + 4) & 63, w = (ww * 8 + tw + 4) & 63;
                long di = (((long)((bb * 8 + d) * 64 + h)) * 64 + w) * 128;
                #pragma unroll
                for (int ni = 0; ni < 4; ++ni) {
                    unsigned int wrd = x1p[mi][ni][r >> 1];
                    float x1v = b2f((ushort)((wrd >> ((r & 1) * 16)) & 0xffffu));
                    out[di + cols[ni]] = x1v + yacc[mi][ni][r] + f2v[ni];
                }
            }
        }
    }
}

// ---------------------------------------------------------------------------
// ws layout (needs ~52.9 MB):
//   [0 .. 50.33MB): qkv window-major [wi][mat][head][tok][16]; K3 overwrites
//                   each window's q-region in-place with attn-out [wi][tok][128].
//   tail: wq 96KB | wp 32KB | wf 256KB | bm 2MB.
// d_out holds ONLY the final f32 output (no scratch -> no races).
// ---------------------------------------------------------------------------
extern "C" void kernel_launch(void* const* d_in, const int* in_sizes, int n_in,
                              void* d_out, int out_size, void* d_ws, size_t ws_size,
                              hipStream_t stream)
{
    (void)in_sizes; (void)n_in; (void)out_size; (void)ws_size;
    const float* x      = (const float*)d_in[0];
    const float* qkv_w  = (const float*)d_in[1];
    const float* qkv_b  = (const float*)d_in[2];
    const float* proj_w = (const float*)d_in[3];
    const float* proj_b = (const float*)d_in[4];
    const float* rpb    = (const float*)d_in[5];
    const float* ln1_g  = (const float*)d_in[6];
    const float* ln1_b  = (const float*)d_in[7];
    const float* ln2_g  = (const float*)d_in[8];
    const float* ln2_b  = (const float*)d_in[9];
    const float* fc1_w  = (const float*)d_in[10];
    const float* fc1_b  = (const float*)d_in[11];
    const float* fc2_w  = (const float*)d_in[12];
    const float* fc2_b  = (const float*)d_in[13];
    float* out = (float*)d_out;

    ushort* qkvb = (ushort*)d_ws;                       // 50.33 MB
    ushort* wq   = (ushort*)((char*)d_ws + 50331648);   // 49152 elems
    ushort* wp   = wq + 49152;                          // 16384
    ushort* wf   = wp + 16384;                          // 131072
    ushort* bm   = wf + 131072;                         // 1048576

    hipLaunchKernelGGL(k0_prep, dim3(832), dim3(256), 0, stream,
                       qkv_w, proj_w, fc1_w, fc2_w, rpb, wq, wp, wf, bm);
    hipLaunchKernelGGL(k2_qkv, dim3(512), dim3(256), 0, stream,
                       x, ln1_g, ln1_b, wq, qkv_b, qkvb);
    hipLaunchKernelGGL(k3_attn, dim3(512), dim3(256), 0, stream, qkvb, bm);
    hipLaunchKernelGGL(k45, dim3(1024), dim3(256), 0, stream,
                       qkvb, wp, proj_b, x, ln2_g, ln2_b,
                       wf, fc1_b, wf + 65536, fc2_b, out);
}

// Round 2
// 291.249 us; speedup vs baseline: 1.0454x; 1.0454x over previous
//
#include <hip/hip_runtime.h>
#include <math.h>

typedef short s16x8 __attribute__((ext_vector_type(8)));
typedef float f32x4 __attribute__((ext_vector_type(4)));

#define MFMA(a, b, c)   __builtin_amdgcn_mfma_f32_16x16x32_bf16(a, b, c, 0, 0, 0)

__device__ __forceinline__ float b2f(ushort u) {
    union { unsigned int i; float f; } v; v.i = ((unsigned int)u) << 16; return v.f;
}
__device__ __forceinline__ ushort f2b(float f) {
    union { float f; unsigned int i; } v; v.f = f;
    unsigned int r = v.i + 0x7fffu + ((v.i >> 16) & 1u);
    return (ushort)(r >> 16);
}
__device__ __forceinline__ float gelu_tanh(float v) {
    float u = 0.7978845608f * (v + 0.044715f * v * v * v);
    float e = __expf(-2.f * fabsf(u));
    float t = (1.f - e) / (1.f + e);            // tanh(|u|)
    t = (u < 0.f) ? -t : t;
    return 0.5f * v * (1.f + t);
}

// ---------------------------------------------------------------------------
// K0: all prep. blocks [0,192): qkv_w->wq; [192,256): proj_w->wp;
// [256,768): fc1/fc2->wf; [768,832): bias+mask table bm[cls][head][128][128].
// ---------------------------------------------------------------------------
__global__ __launch_bounds__(256) void k0_prep(
    const float* __restrict__ qkv_w, const float* __restrict__ proj_w,
    const float* __restrict__ fc1_w, const float* __restrict__ fc2_w,
    const float* __restrict__ rpb, ushort* __restrict__ wq,
    ushort* __restrict__ wp, ushort* __restrict__ wf, ushort* __restrict__ bm)
{
    int bid = blockIdx.x, tid = threadIdx.x;
    if (bid < 192) { int idx = bid * 256 + tid; wq[idx] = f2b(qkv_w[idx]); return; }
    if (bid < 256) { int idx = (bid - 192) * 256 + tid; wp[idx] = f2b(proj_w[idx]); return; }
    if (bid < 768) {
        int idx = (bid - 256) * 256 + tid;
        wf[idx] = f2b(idx < 65536 ? fc1_w[idx] : fc2_w[idx - 65536]);
        return;
    }
    int bi = bid - 768;                             // [0,64) = cls*8+head
    int cls = bi >> 3, head = bi & 7;
    int ed = (cls >> 2) & 1, eh = (cls >> 1) & 1, ew = cls & 1;
    int j = tid & 127;
    int tdj = j >> 6, thj = (j >> 3) & 7, twj = j & 7;
    int regj = (ed ? (tdj + 1) : 0) * 9
             + (eh ? ((thj < 4) ? 1 : 2) : 0) * 3
             + (ew ? ((twj < 4) ? 1 : 2) : 0);
    ushort* bmp = bm + (long)bi * 16384;
    for (int ii = 0; ii < 64; ++ii) {
        int i = (tid >> 7) * 64 + ii;
        int tdi = i >> 6, thi = (i >> 3) & 7, twi = i & 7;
        int regi = (ed ? (tdi + 1) : 0) * 9
                 + (eh ? ((thi < 4) ? 1 : 2) : 0) * 3
                 + (ew ? ((twi < 4) ? 1 : 2) : 0);
        int rpi = (tdi - tdj + 1) * 225 + (thi - thj + 7) * 15 + (twi - twj + 7);
        float v = rpb[rpi * 8 + head] + ((regi != regj) ? -100.f : 0.f);
        bmp[i * 128 + j] = f2b(v);
    }
}

// ---------------------------------------------------------------------------
// K2: fused LN1 + cyclic-shift + window gather + QKV GEMM.
// Output WINDOW-major: qkv[wi][mat][head][token][16] (strides 49152/16384/2048/16).
// ---------------------------------------------------------------------------
__global__ __launch_bounds__(256) void k2_qkv(
    const float* __restrict__ x, const float* __restrict__ g,
    const float* __restrict__ be, const ushort* __restrict__ wq,
    const float* __restrict__ qkv_b, ushort* __restrict__ qkv)
{
    __shared__ __align__(16) ushort As[128][136];
    int tid = threadIdx.x;
    int m0 = blockIdx.x * 128;
    {   // LN + shift + gather -> As (2 threads per row)
        int row = tid >> 1, half = tid & 1;
        int tk = m0 + row;
        int wi = tk >> 7, t = tk & 127;
        int b = wi >> 8, wd = (wi >> 6) & 3, wh = (wi >> 3) & 7, ww = wi & 7;
        int td = t >> 6, th = (t >> 3) & 7, tw = t & 7;
        int d = (wd * 2 + td + 1) & 7;
        int h = (wh * 8 + th + 4) & 63;
        int w = (ww * 8 + tw + 4) & 63;
        long src = (((long)((b * 8 + d) * 64 + h)) * 64 + w) * 128 + half * 64;
        float vals[64];
        float s = 0.f, q = 0.f;
        #pragma unroll
        for (int i = 0; i < 16; ++i) {
            float4 u = *(const float4*)&x[src + i * 4];
            vals[i * 4 + 0] = u.x; vals[i * 4 + 1] = u.y;
            vals[i * 4 + 2] = u.z; vals[i * 4 + 3] = u.w;
            s += u.x + u.y + u.z + u.w;
            q += u.x * u.x + u.y * u.y + u.z * u.z + u.w * u.w;
        }
        s += __shfl_xor(s, 1);
        q += __shfl_xor(q, 1);
        float mean = s * (1.f / 128.f);
        float rstd = rsqrtf(q * (1.f / 128.f) - mean * mean + 1e-5f);
        #pragma unroll
        for (int i = 0; i < 8; ++i) {
            ushort pk[8];
            #pragma unroll
            for (int jj = 0; jj < 8; ++jj) {
                int c = half * 64 + i * 8 + jj;
                pk[jj] = f2b((vals[i * 8 + jj] - mean) * rstd * g[c] + be[c]);
            }
            *(uint4*)&As[row][half * 64 + i * 8] = *(uint4*)pk;
        }
    }
    __syncthreads();
    int wv = tid >> 6, lane = tid & 63, li = lane & 15, quad = lane >> 4;
    int wm = wv >> 1, wn = wv & 1;
    long wibase = (long)(m0 >> 7) * 49152;
    for (int nb = 0; nb < 3; ++nb) {
        f32x4 acc[4][4] = {};
        for (int s = 0; s < 4; ++s) {
            s16x8 a[4], bw[4];
            #pragma unroll
            for (int mi = 0; mi < 4; ++mi)
                a[mi] = *(const s16x8*)&As[wm * 64 + mi * 16 + li][s * 32 + quad * 8];
            #pragma unroll
            for (int ni = 0; ni < 4; ++ni)
                bw[ni] = *(const s16x8*)&wq[(long)(nb * 128 + wn * 64 + ni * 16 + li) * 128
                                            + s * 32 + quad * 8];
            #pragma unroll
            for (int mi = 0; mi < 4; ++mi)
                #pragma unroll
                for (int ni = 0; ni < 4; ++ni)
                    acc[mi][ni] = MFMA(a[mi], bw[ni], acc[mi][ni]);
        }
        #pragma unroll
        for (int mi = 0; mi < 4; ++mi)
            #pragma unroll
            for (int ni = 0; ni < 4; ++ni) {
                int gcol = nb * 128 + wn * 64 + ni * 16 + li;
                int mat = gcol >> 7, hd = (gcol >> 4) & 7;
                float bias = qkv_b[gcol];
                float scale = (mat == 0) ? 0.25f : 1.f;   // SCALE = 16^-0.5
                long base2 = wibase + mat * 16384 + hd * 2048 + li;
                #pragma unroll
                for (int r = 0; r < 4; ++r) {
                    int trow = wm * 64 + mi * 16 + quad * 4 + r;
                    qkv[base2 + trow * 16] = f2b((acc[mi][ni][r] + bias) * scale);
                }
            }
    }
}

// ---------------------------------------------------------------------------
// K3: one block per WINDOW, 8 heads sequential. QK^T (16x16x32, d zero-padded),
// bias+mask table, softmax, PV. O held in registers across heads, then written
// in-place over the (dead) q-region of this window: ao[wi][token][128ch].
// ---------------------------------------------------------------------------
__global__ __launch_bounds__(256) void k3_attn(
    ushort* __restrict__ qkv, const ushort* __restrict__ bm)
{
    __shared__ __align__(16) ushort qs[128][40];
    __shared__ __align__(16) ushort ks[128][40];
    __shared__ __align__(16) ushort vt[16][136];
    __shared__ __align__(16) ushort ps[128][136];
    int wi = blockIdx.x;
    int wd = (wi >> 6) & 3, wh = (wi >> 3) & 7, ww = wi & 7;
    int cls = ((wd == 3) << 2) | ((wh == 7) << 1) | (ww == 7);
    int tid = threadIdx.x;
    int wv = tid >> 6, lane = tid & 63, li = lane & 15, quad = lane >> 4;
    long wbase = (long)wi * 49152;
    uint2 opk[8][2];
    for (int h = 0; h < 8; ++h) {
        __syncthreads();   // previous head's PV readers done before restage
        {   int token = tid >> 1, dd0 = (tid & 1) * 8;
            long tb = wbase + h * 2048 + token * 16 + dd0;
            uint4 qv = *(const uint4*)&qkv[tb];
            uint4 kv = *(const uint4*)&qkv[tb + 16384];
            uint4 vv = *(const uint4*)&qkv[tb + 32768];
            uint4 z = {0, 0, 0, 0};
            *(uint4*)&qs[token][dd0] = qv;
            *(uint4*)&ks[token][dd0] = kv;
            *(uint4*)&qs[token][16 + dd0] = z;
            *(uint4*)&ks[token][16 + dd0] = z;
            const ushort* pv = (const ushort*)&vv;
            #pragma unroll
            for (int j = 0; j < 8; ++j) vt[dd0 + j][token] = pv[j];
        }
        __syncthreads();
        f32x4 sacc[2][8] = {};
        s16x8 a[2];
        #pragma unroll
        for (int mi = 0; mi < 2; ++mi)
            a[mi] = *(const s16x8*)&qs[wv * 32 + mi * 16 + li][quad * 8];
        #pragma unroll
        for (int ni = 0; ni < 8; ++ni) {
            s16x8 bf = *(const s16x8*)&ks[ni * 16 + li][quad * 8];
            #pragma unroll
            for (int mi = 0; mi < 2; ++mi) sacc[mi][ni] = MFMA(a[mi], bf, sacc[mi][ni]);
        }
        long bmbase = (long)(cls * 8 + h) * 16384;
        #pragma unroll
        for (int mi = 0; mi < 2; ++mi) {
            #pragma unroll
            for (int r = 0; r < 4; ++r) {
                int i = wv * 32 + mi * 16 + quad * 4 + r;
                float sv[8];
                float rowmax = -1e30f;
                #pragma unroll
                for (int ni = 0; ni < 8; ++ni) {
                    float v = sacc[mi][ni][r] + b2f(bm[bmbase + i * 128 + ni * 16 + li]);
                    sv[ni] = v;
                    rowmax = fmaxf(rowmax, v);
                }
                #pragma unroll
                for (int m = 1; m < 16; m <<= 1) rowmax = fmaxf(rowmax, __shfl_xor(rowmax, m));
                float sum = 0.f;
                #pragma unroll
                for (int ni = 0; ni < 8; ++ni) { sv[ni] = __expf(sv[ni] - rowmax); sum += sv[ni]; }
                #pragma unroll
                for (int m = 1; m < 16; m <<= 1) sum += __shfl_xor(sum, m);
                float inv = 1.f / sum;
                #pragma unroll
                for (int ni = 0; ni < 8; ++ni) ps[i][ni * 16 + li] = f2b(sv[ni] * inv);
            }
        }
        __syncthreads();
        f32x4 pacc[2] = {};
        #pragma unroll
        for (int kk = 0; kk < 4; ++kk) {
            s16x8 bv = *(const s16x8*)&vt[li][kk * 32 + quad * 8];
            #pragma unroll
            for (int mi = 0; mi < 2; ++mi) {
                s16x8 ap = *(const s16x8*)&ps[wv * 32 + mi * 16 + li][kk * 32 + quad * 8];
                pacc[mi] = MFMA(ap, bv, pacc[mi]);
            }
        }
        #pragma unroll
        for (int mi = 0; mi < 2; ++mi) {
            opk[h][mi].x = (unsigned int)f2b(pacc[mi][0]) | ((unsigned int)f2b(pacc[mi][1]) << 16);
            opk[h][mi].y = (unsigned int)f2b(pacc[mi][2]) | ((unsigned int)f2b(pacc[mi][3]) << 16);
        }
    }
    // all q/k/v of this window consumed -> safe to overwrite q-region with O
    #pragma unroll
    for (int h = 0; h < 8; ++h)
        #pragma unroll
        for (int mi = 0; mi < 2; ++mi) {
            unsigned int w0 = opk[h][mi].x, w1 = opk[h][mi].y;
            #pragma unroll
            for (int r = 0; r < 4; ++r) {
                unsigned int word = (r < 2) ? w0 : w1;
                ushort v = (ushort)((word >> ((r & 1) * 16)) & 0xffff);
                int i = wv * 32 + mi * 16 + quad * 4 + r;
                qkv[wbase + (long)i * 128 + h * 16 + li] = v;
            }
        }
}

// ---------------------------------------------------------------------------
// K45: fused proj GEMM + bias + residual + LN2 + FC1 + gelu + FC2 + residual
// + window-reverse/unshift scattered f32 store. 64-token tile, 1024 blocks.
// R1: x1 kept in 16 packed bf16x2 VGPRs (was 16.9KB x1t LDS); LN2 stats via
// 16-lane shfl butterfly + redS[2][64] cross-wave combine. LDS 52.7->34.8KB.
// R2: launch_bounds back to plain 256 — the (256,4) bound made the backend
// clamp to 64 VGPR and spill ~280B/thread to scratch (FETCH/WRITE tripled).
// ---------------------------------------------------------------------------
__global__ __launch_bounds__(256) void k45(
    const ushort* __restrict__ ao, const ushort* __restrict__ wp,
    const float* __restrict__ proj_b, const float* __restrict__ x,
    const float* __restrict__ g2, const float* __restrict__ be2,
    const ushort* __restrict__ wf1, const float* __restrict__ fc1_b,
    const ushort* __restrict__ wf2, const float* __restrict__ fc2_b,
    float* __restrict__ out)
{
    __shared__ __align__(16) ushort As[64][132];    // ao tile, later xs (LN2 out)
    __shared__ __align__(16) ushort hs[64][132];    // gelu(h) chunk
    __shared__ float redS[2][64];
    __shared__ float redQ[2][64];
    int tid = threadIdx.x;
    int b = blockIdx.x;
    int wi = b >> 1, half64 = b & 1;
    int wd = (wi >> 6) & 3, wh = (wi >> 3) & 7, ww = wi & 7;
    int bb = wi >> 8;
    long aobase = (long)wi * 49152 + half64 * 8192;
    #pragma unroll
    for (int i = 0; i < 4; ++i) {
        int slot = tid + i * 256;
        int row = slot >> 4, c8 = (slot & 15) * 8;
        *(uint4*)&As[row][c8] = *(const uint4*)&ao[aobase + row * 128 + c8];
    }
    __syncthreads();
    int wv = tid >> 6, lane = tid & 63, li = lane & 15, quad = lane >> 4;
    int wm = wv >> 1, wn = wv & 1;
    f32x4 acc[2][4] = {};
    for (int s = 0; s < 4; ++s) {
        s16x8 a[2], bw[4];
        #pragma unroll
        for (int mi = 0; mi < 2; ++mi)
            a[mi] = *(const s16x8*)&As[wm * 32 + mi * 16 + li][s * 32 + quad * 8];
        #pragma unroll
        for (int ni = 0; ni < 4; ++ni)
            bw[ni] = *(const s16x8*)&wp[(long)(wn * 64 + ni * 16 + li) * 128 + s * 32 + quad * 8];
        #pragma unroll
        for (int mi = 0; mi < 2; ++mi)
            #pragma unroll
            for (int ni = 0; ni < 4; ++ni)
                acc[mi][ni] = MFMA(a[mi], bw[ni], acc[mi][ni]);
    }
    // epilogue: x1 = acc + proj_b + x (f32, in-place in acc); LN2 row partials
    int cols[4];
    #pragma unroll
    for (int ni = 0; ni < 4; ++ni) cols[ni] = wn * 64 + ni * 16 + li;
    {
        float pbv[4];
        #pragma unroll
        for (int ni = 0; ni < 4; ++ni) pbv[ni] = proj_b[cols[ni]];
        #pragma unroll
        for (int mi = 0; mi < 2; ++mi) {
            #pragma unroll
            for (int r = 0; r < 4; ++r) {
                int lrow = wm * 32 + mi * 16 + quad * 4 + r;
                int t = half64 * 64 + lrow;
                int td = t >> 6, th = (t >> 3) & 7, tw = t & 7;
                int d = (wd * 2 + td + 1) & 7, h = (wh * 8 + th + 4) & 63, w = (ww * 8 + tw + 4) & 63;
                long di = (((long)((bb * 8 + d) * 64 + h)) * 64 + w) * 128;
                float s_ = 0.f, q_ = 0.f;
                #pragma unroll
                for (int ni = 0; ni < 4; ++ni) {
                    float v = acc[mi][ni][r] + pbv[ni] + x[di + cols[ni]];
                    acc[mi][ni][r] = v;
                    s_ += v; q_ += v * v;
                }
                #pragma unroll
                for (int m = 1; m < 16; m <<= 1) {
                    s_ += __shfl_xor(s_, m);
                    q_ += __shfl_xor(q_, m);
                }
                if (li == 0) { redS[wn][lrow] = s_; redQ[wn][lrow] = q_; }
            }
        }
    }
    __syncthreads();
    // LN2 normalize -> As (xs); pack x1 -> bf16x2 regs
    {
        float g2v[4], be2v[4];
        #pragma unroll
        for (int ni = 0; ni < 4; ++ni) { g2v[ni] = g2[cols[ni]]; be2v[ni] = be2[cols[ni]]; }
        #pragma unroll
        for (int mi = 0; mi < 2; ++mi) {
            #pragma unroll
            for (int r = 0; r < 4; ++r) {
                int lrow = wm * 32 + mi * 16 + quad * 4 + r;
                float tS = redS[0][lrow] + redS[1][lrow];
                float tQ = redQ[0][lrow] + redQ[1][lrow];
                float mean = tS * (1.f / 128.f);
                float rstd = rsqrtf(tQ * (1.f / 128.f) - mean * mean + 1e-5f);
                #pragma unroll
                for (int ni = 0; ni < 4; ++ni)
                    As[lrow][cols[ni]] = f2b((acc[mi][ni][r] - mean) * rstd * g2v[ni] + be2v[ni]);
            }
        }
    }
    uint x1p[2][4][2];
    #pragma unroll
    for (int mi = 0; mi < 2; ++mi)
        #pragma unroll
        for (int ni = 0; ni < 4; ++ni)
            #pragma unroll
            for (int rr = 0; rr < 2; ++rr)
                x1p[mi][ni][rr] = (unsigned int)f2b(acc[mi][ni][2 * rr])
                                | ((unsigned int)f2b(acc[mi][ni][2 * rr + 1]) << 16);
    __syncthreads();
    f32x4 yacc[2][4] = {};
    for (int hc = 0; hc < 4; ++hc) {
        f32x4 hacc[2][4] = {};
        #pragma unroll
        for (int kk = 0; kk < 4; ++kk) {
            s16x8 a[2], bw[4];
            #pragma unroll
            for (int mi = 0; mi < 2; ++mi)
                a[mi] = *(const s16x8*)&As[wm * 32 + mi * 16 + li][kk * 32 + quad * 8];
            #pragma unroll
            for (int ni = 0; ni < 4; ++ni)
                bw[ni] = *(const s16x8*)&wf1[(long)(hc * 128 + wn * 64 + ni * 16 + li) * 128
                                             + kk * 32 + quad * 8];
            #pragma unroll
            for (int mi = 0; mi < 2; ++mi)
                #pragma unroll
                for (int ni = 0; ni < 4; ++ni)
                    hacc[mi][ni] = MFMA(a[mi], bw[ni], hacc[mi][ni]);
        }
        #pragma unroll
        for (int mi = 0; mi < 2; ++mi)
            #pragma unroll
            for (int ni = 0; ni < 4; ++ni) {
                int col = wn * 64 + ni * 16 + li;
                float bbv = fc1_b[hc * 128 + col];
                #pragma unroll
                for (int r = 0; r < 4; ++r) {
                    int row = wm * 32 + mi * 16 + quad * 4 + r;
                    hs[row][col] = f2b(gelu_tanh(hacc[mi][ni][r] + bbv));
                }
            }
        __syncthreads();
        #pragma unroll
        for (int kk = 0; kk < 4; ++kk) {
            s16x8 a[2], bw[4];
            #pragma unroll
            for (int mi = 0; mi < 2; ++mi)
                a[mi] = *(const s16x8*)&hs[wm * 32 + mi * 16 + li][kk * 32 + quad * 8];
            #pragma unroll
            for (int ni = 0; ni < 4; ++ni)
                bw[ni] = *(const s16x8*)&wf2[(long)(wn * 64 + ni * 16 + li) * 512
                                             + hc * 128 + kk * 32 + quad * 8];
            #pragma unroll
            for (int mi = 0; mi < 2; ++mi)
                #pragma unroll
                for (int ni = 0; ni < 4; ++ni)
                    yacc[mi][ni] = MFMA(a[mi], bw[ni], yacc[mi][ni]);
        }
        __syncthreads();
    }
    {
        float f2v[4];
        #pragma unroll
        for (int ni = 0; ni < 4; ++ni) f2v[ni] = fc2_b[cols[ni]];
        #pragma unroll
        for (int mi = 0; mi < 2; ++mi) {
            #pragma unroll
            for (int r = 0; r < 4; ++r) {
                int lrow = wm * 32 + mi * 16 + quad * 4 + r;
                int t = half64 * 64 + lrow;
                int td = t >> 6, th = (t >> 3) & 7, tw = t & 7;
                int d = (wd * 2 + td + 1) & 7, h = (wh * 8 + th + 4) & 63, w = (ww * 8 + tw + 4) & 63;
                long di = (((long)((bb * 8 + d) * 64 + h)) * 64 + w) * 128;
                #pragma unroll
                for (int ni = 0; ni < 4; ++ni) {
                    unsigned int wrd = x1p[mi][ni][r >> 1];
                    float x1v = b2f((ushort)((wrd >> ((r & 1) * 16)) & 0xffffu));
                    out[di + cols[ni]] = x1v + yacc[mi][ni][r] + f2v[ni];
                }
            }
        }
    }
}

// ---------------------------------------------------------------------------
// ws layout (needs ~52.9 MB):
//   [0 .. 50.33MB): qkv window-major [wi][mat][head][tok][16]; K3 overwrites
//                   each window's q-region in-place with attn-out [wi][tok][128].
//   tail: wq 96KB | wp 32KB | wf 256KB | bm 2MB.
// d_out holds ONLY the final f32 output (no scratch -> no races).
// ---------------------------------------------------------------------------
extern "C" void kernel_launch(void* const* d_in, const int* in_sizes, int n_in,
                              void* d_out, int out_size, void* d_ws, size_t ws_size,
                              hipStream_t stream)
{
    (void)in_sizes; (void)n_in; (void)out_size; (void)ws_size;
    const float* x      = (const float*)d_in[0];
    const float* qkv_w  = (const float*)d_in[1];
    const float* qkv_b  = (const float*)d_in[2];
    const float* proj_w = (const float*)d_in[3];
    const float* proj_b = (const float*)d_in[4];
    const float* rpb    = (const float*)d_in[5];
    const float* ln1_g  = (const float*)d_in[6];
    const float* ln1_b  = (const float*)d_in[7];
    const float* ln2_g  = (const float*)d_in[8];
    const float* ln2_b  = (const float*)d_in[9];
    const float* fc1_w  = (const float*)d_in[10];
    const float* fc1_b  = (const float*)d_in[11];
    const float* fc2_w  = (const float*)d_in[12];
    const float* fc2_b  = (const float*)d_in[13];
    float* out = (float*)d_out;

    ushort* qkvb = (ushort*)d_ws;                       // 50.33 MB
    ushort* wq   = (ushort*)((char*)d_ws + 50331648);   // 49152 elems
    ushort* wp   = wq + 49152;                          // 16384
    ushort* wf   = wp + 16384;                          // 131072
    ushort* bm   = wf + 131072;                         // 1048576

    hipLaunchKernelGGL(k0_prep, dim3(832), dim3(256), 0, stream,
                       qkv_w, proj_w, fc1_w, fc2_w, rpb, wq, wp, wf, bm);
    hipLaunchKernelGGL(k2_qkv, dim3(512), dim3(256), 0, stream,
                       x, ln1_g, ln1_b, wq, qkv_b, qkvb);
    hipLaunchKernelGGL(k3_attn, dim3(512), dim3(256), 0, stream, qkvb, bm);
    hipLaunchKernelGGL(k45, dim3(1024), dim3(256), 0, stream,
                       qkvb, wp, proj_b, x, ln2_g, ln2_b,
                       wf, fc1_b, wf + 65536, fc2_b, out);
}